// Round 17
// baseline (130.731 us; speedup 1.0000x reference)
//
#include <hip/hip_runtime.h>
#include <stdint.h>

#define Bsz 2
#define Ssz 2048
#define Dsz 1024
#define Hsz 16
#define DKsz 64

typedef __attribute__((ext_vector_type(8))) short sh8;
typedef __attribute__((ext_vector_type(4))) float fx4;
typedef __attribute__((ext_vector_type(16))) float fx16;
typedef __attribute__((ext_vector_type(4))) unsigned ux4;

__device__ __forceinline__ unsigned short f2bf(float x) {
  uint32_t u = __builtin_bit_cast(uint32_t, x);
  uint32_t r = (u + 0x7fffu + ((u >> 16) & 1u)) >> 16;
  return (unsigned short)r;
}

__device__ __forceinline__ fx4 mfma16(sh8 a, sh8 b, fx4 c) {
  return __builtin_amdgcn_mfma_f32_16x16x32_bf16(a, b, c, 0, 0, 0);
}

__device__ __forceinline__ fx16 mfma32(sh8 a, sh8 b, fx16 c) {
  return __builtin_amdgcn_mfma_f32_32x32x16_bf16(a, b, c, 0, 0, 0);
}

__device__ __forceinline__ void g2l16(const void* g, void* l) {
  __builtin_amdgcn_global_load_lds((const __attribute__((address_space(1))) void*)g,
                                   (__attribute__((address_space(3))) void*)l, 16, 0, 0);
}

__device__ __forceinline__ float fexp2(float x) {
#if __has_builtin(__builtin_amdgcn_exp2f)
  return __builtin_amdgcn_exp2f(x);
#else
  return exp2f(x);
#endif
}

__device__ __forceinline__ unsigned cvtpk(float lo, float hi) {
  unsigned r;
  asm("v_cvt_pk_bf16_f32 %0, %1, %2" : "=v"(r) : "v"(lo), "v"(hi));
  return r;
}

// v_permlane32_swap_b32: after, a = {a.lo, b.lo}, b = {a.hi, b.hi}
__device__ __forceinline__ void plswap(unsigned& a, unsigned& b) {
  asm("v_permlane32_swap_b32 %0, %1" : "+v"(a), "+v"(b));
}

// Build two PV B-operand fragments (k=16 each) from one 32-kv score tile.
__device__ __forceinline__ void build_pa(const fx16& p, sh8& pa0, sh8& pa1) {
  unsigned w0 = cvtpk(p[0], p[1]), w1 = cvtpk(p[2], p[3]);
  unsigned w2 = cvtpk(p[4], p[5]), w3 = cvtpk(p[6], p[7]);
  unsigned w4 = cvtpk(p[8], p[9]), w5 = cvtpk(p[10], p[11]);
  unsigned w6 = cvtpk(p[12], p[13]), w7 = cvtpk(p[14], p[15]);
  plswap(w0, w2);
  plswap(w1, w3);
  ux4 u0 = {w0, w1, w2, w3};
  pa0 = __builtin_bit_cast(sh8, u0);
  plswap(w4, w6);
  plswap(w5, w7);
  ux4 u1 = {w4, w5, w6, w7};
  pa1 = __builtin_bit_cast(sh8, u1);
}

// ------- fp32 -> bf16 conversion of the 4 weights + fused mask all-ones check -------
__global__ __launch_bounds__(256) void convert_kernel(
    const float* __restrict__ wq, const float* __restrict__ wk, const float* __restrict__ wv,
    const float* __restrict__ wo, const int* __restrict__ mask,
    unsigned short* __restrict__ wqb, unsigned short* __restrict__ wkb,
    unsigned short* __restrict__ wvb, unsigned short* __restrict__ wob,
    int* __restrict__ flag) {
  const int NW = Dsz * Dsz / 4;
  const int NC = 4 * NW;
  const int NM = Bsz * Ssz * Ssz / 4;  // mask chunks of int4
  const int total = NC + NM;
  int bad = 0;
  for (int i = blockIdx.x * blockDim.x + threadIdx.x; i < total; i += gridDim.x * blockDim.x) {
    if (i >= NC) {
      int4 m = ((const int4*)mask)[i - NC];
      if (m.x == 0 || m.y == 0 || m.z == 0 || m.w == 0) bad = 1;
      continue;
    }
    int t = i / NW, off = i - t * NW;
    const float* src = (t == 0) ? wq : ((t == 1) ? wk : ((t == 2) ? wv : wo));
    unsigned short* dst = (t == 0) ? wqb : ((t == 1) ? wkb : ((t == 2) ? wvb : wob));
    float4 x = ((const float4*)src)[off];
    ushort4 o;
    o.x = f2bf(x.x); o.y = f2bf(x.y); o.z = f2bf(x.z); o.w = f2bf(x.w);
    ((ushort4*)dst)[off] = o;
  }
  if (bad) atomicAnd(flag, 0);
}

// ---------------- QKV projection GEMM: C = X(fp32) @ W^T + b, bf16 MFMA, 128x64 tile ------
// (unchanged from R16)
__global__ __launch_bounds__(256) void proj_qkv_kernel(
    const float* __restrict__ qf, const float* __restrict__ kf, const float* __restrict__ vf,
    const unsigned short* __restrict__ wqb, const unsigned short* __restrict__ wkb,
    const unsigned short* __restrict__ wvb,
    const float* __restrict__ bq, const float* __restrict__ bk, const float* __restrict__ bv,
    unsigned short* __restrict__ qh, unsigned short* __restrict__ kh,
    unsigned short* __restrict__ vt) {
  __shared__ __align__(16) unsigned short SMEM[12288];
  unsigned short* Ts = SMEM;
  const int z = blockIdx.z;
  const float* X = (z == 0) ? qf : ((z == 1) ? kf : vf);
  const unsigned short* W = (z == 0) ? wqb : ((z == 1) ? wkb : wvb);
  const float* bias = (z == 0) ? bq : ((z == 1) ? bk : bv);
  const int m0 = blockIdx.x * 128, n0 = blockIdx.y * 64;
  const int tid = threadIdx.x, lane = tid & 63, wid = tid >> 6;
  const int wm = wid >> 1, wn = wid & 1;
  const int c = lane & 15, g = lane >> 4;
  fx4 acc[4][2] = {};

  auto LOADA = [&](int k0, float4* a) {
#pragma unroll
    for (int i = 0; i < 4; i++) {
      int c4 = i * 256 + tid;
      a[i] = *(const float4*)(X + (size_t)(m0 + (c4 >> 3)) * Dsz + k0 + (c4 & 7) * 4);
    }
  };
  auto WRITEA = [&](const float4* a, unsigned short* As) {
#pragma unroll
    for (int i = 0; i < 4; i++) {
      int c4 = i * 256 + tid;
      uint2 w;
      w.x = cvtpk(a[i].x, a[i].y);
      w.y = cvtpk(a[i].z, a[i].w);
      *(uint2*)&As[(c4 >> 3) * 32 + (c4 & 7) * 4] = w;
    }
  };
  auto G2LB = [&](int k0, unsigned short* Bs) {
    g2l16(W + (size_t)(n0 + (tid >> 2)) * Dsz + k0 + (tid & 3) * 8,
          (char*)Bs + (size_t)(wid * 64) * 16);
  };
  auto COMPUTE = [&](const unsigned short* As, const unsigned short* Bs) {
    sh8 af[4], bfr[2];
#pragma unroll
    for (int m = 0; m < 4; m++)
      af[m] = *(const sh8*)&As[(wm * 64 + m * 16 + c) * 32 + g * 8];
#pragma unroll
    for (int n = 0; n < 2; n++)
      bfr[n] = *(const sh8*)&Bs[(wn * 32 + n * 16 + c) * 32 + g * 8];
#pragma unroll
    for (int m = 0; m < 4; m++)
#pragma unroll
      for (int n = 0; n < 2; n++)
        acc[m][n] = mfma16(af[m], bfr[n], acc[m][n]);
  };

  float4 aA[4], aB[4];
  LOADA(0, aA);
  G2LB(0, SMEM + 8192);
  WRITEA(aA, SMEM);
  __syncthreads();
#pragma unroll 1
  for (int j = 0; j < 16; j++) {
    const int k0 = j * 64;
    if (k0 + 32 < Dsz) { LOADA(k0 + 32, aB); G2LB(k0 + 32, SMEM + 10240); }
    COMPUTE(SMEM, SMEM + 8192);
    if (k0 + 32 < Dsz) WRITEA(aB, SMEM + 4096);
    __syncthreads();
    if (k0 + 64 < Dsz) { LOADA(k0 + 64, aA); G2LB(k0 + 64, SMEM + 8192); }
    if (k0 + 32 < Dsz) COMPUTE(SMEM + 4096, SMEM + 10240);
    if (k0 + 64 < Dsz) WRITEA(aA, SMEM);
    __syncthreads();
  }

  const float CE = 0.18033688011112042f;  // log2(e)/sqrt(64), folded into Q
  if (z < 2) {
    unsigned short* O = (z == 0) ? qh : kh;
    const float sc = (z == 0) ? CE : 1.0f;
#pragma unroll
    for (int n = 0; n < 2; n++) {
      int nl = wn * 32 + n * 16 + c;
      float bj = bias[n0 + nl];
#pragma unroll
      for (int m = 0; m < 4; m++)
#pragma unroll
        for (int r = 0; r < 4; r++) {
          int ml = wm * 64 + m * 16 + g * 4 + r;
          Ts[ml * 72 + nl] = f2bf((acc[m][n][r] + bj) * sc);
        }
    }
    __syncthreads();
    const int h = n0 >> 6;
#pragma unroll
    for (int it = 0; it < 4; it++) {
      int ch = it * 256 + tid;
      int row = ch >> 3, off = ch & 7;
      sh8 dv = *(const sh8*)&Ts[row * 72 + off * 8];
      int i = m0 + row;
      int b = i >> 11, s = i & 2047;
      *(sh8*)&O[(((size_t)(b * Hsz + h) * Ssz + s) << 6) + off * 8] = dv;
    }
  } else {
#pragma unroll
    for (int n = 0; n < 2; n++) {
      int nl = wn * 32 + n * 16 + c;
      float bj = bias[n0 + nl];
#pragma unroll
      for (int m = 0; m < 4; m++)
#pragma unroll
        for (int r = 0; r < 4; r++) {
          int ml = wm * 64 + m * 16 + g * 4 + r;
          Ts[nl * 136 + ml] = f2bf(acc[m][n][r] + bj);
        }
    }
    __syncthreads();
    int b = m0 >> 11, sbase = m0 & 2047;
    const int h = n0 >> 6;
#pragma unroll
    for (int it = 0; it < 4; it++) {
      int ch = it * 256 + tid;
      int row = ch >> 4, off = ch & 15;
      sh8 dv = *(const sh8*)&Ts[row * 136 + off * 8];
      int dk = (n0 + row) & 63;
      *(sh8*)&vt[(size_t)((b * Hsz + h) * DKsz + dk) * Ssz + sbase + off * 8] = dv;
    }
  }
}

// ---------------- flash attention: KVBLK=32, KV-split x2, 3-buffer depth-2 pipeline ----
// STAGE(t+2) issued at tile t; barrier waits vmcnt(2) (ordered retirement: 2 outstanding
// = stage(t+2) only => stage(t+1) landed). Stage latency gets a full tile of cover.
// LDS: 2 grp x 3 buf x 8KB = 48KB + combine union (35840B aliases) -> 49152B; grid is
// 2 blocks/CU so 98KB/CU < 160KB (occupancy unchanged).
__global__ __launch_bounds__(512, 4) void attn_kernel(
    const unsigned short* __restrict__ qh, const unsigned short* __restrict__ kh,
    const unsigned short* __restrict__ vt, const int* __restrict__ mask,
    const int* __restrict__ flag, unsigned short* __restrict__ concat) {
  __shared__ __align__(16) unsigned short SMEM[24576];  // grp*12288 + buf*4096
  const int tid = threadIdx.x, lane = tid & 63, wid = tid >> 6;
  const int grp = wid >> 2, w4 = wid & 3;
  const int fid = blockIdx.y * gridDim.x + blockIdx.x;
  const int logical = (fid & 7) * 64 + (fid >> 3);
  const int bh = logical >> 4, qblk = logical & 15;
  const int b = bh >> 4, h = bh & 15;
  const int q0 = qblk * 128 + w4 * 32;
  const int c = lane & 31, hi = lane >> 5;
  const int kvbase = grp * (Ssz / 2);
  const unsigned short* Qb = qh + ((size_t)bh * Ssz + q0) * DKsz;
  const unsigned short* Kb = kh + (size_t)bh * Ssz * DKsz;
  const unsigned short* Vb = vt + (size_t)bh * DKsz * Ssz;
  const int chk = w4 * 64 + lane;
  const int krow = chk >> 3, ksl = (chk & 7) ^ (krow & 7);
  const int koff = krow * DKsz + ksl * 8;
  const int vrow = chk >> 2, vsl = (chk & 3) ^ (vrow & 3);
  const size_t voff = (size_t)vrow * Ssz + vsl * 8;

  sh8 qf[4];
#pragma unroll
  for (int ks = 0; ks < 4; ks++)
    qf[ks] = *(const sh8*)&Qb[(size_t)c * DKsz + ks * 16 + hi * 8];
  const bool allones = (flag[0] != 0);
  float lsum = 0.f;
  fx16 o0 = {}, o1 = {};

  auto STAGE = [&](int bufi, int kv0) {
    unsigned short* base = SMEM + grp * 12288 + bufi * 4096;
    g2l16(Kb + (size_t)kv0 * DKsz + koff, (char*)base + w4 * 1024);
    g2l16(Vb + kv0 + voff, (char*)(base + 2048) + w4 * 1024);
  };

  const int NT = (Ssz / 2) / 32;  // 32 tiles per group
  STAGE(0, kvbase);
  STAGE(1, kvbase + 32);
  asm volatile("s_waitcnt vmcnt(2)" ::: "memory");  // stage(0) landed; stage(1) in flight
  __builtin_amdgcn_s_barrier();
  asm volatile("" ::: "memory");

  int cur = 0;
  for (int t = 0; t < NT; ++t) {
    const int kv0 = kvbase + t * 32;
    int nxt2 = cur + 2; if (nxt2 >= 3) nxt2 -= 3;
    if (t + 2 < NT) STAGE(nxt2, kv0 + 64);
    const unsigned short* Kt = SMEM + grp * 12288 + cur * 4096;
    const unsigned short* Vt = Kt + 2048;
    // ---- QK^T from LDS (32 kv rows x 64 d) ----
    fx16 s0 = {};
    __builtin_amdgcn_s_setprio(1);
#pragma unroll
    for (int ks = 0; ks < 4; ks++) {
      int sl = (2 * ks + hi) ^ (c & 7);
      sh8 ka = *(const sh8*)&Kt[c * 64 + sl * 8];
      s0 = mfma32(ka, qf[ks], s0);
    }
    __builtin_amdgcn_s_setprio(0);
    if (!allones) {
      const int* mrow = mask + ((size_t)b * Ssz + (q0 + c)) * Ssz + kv0;
#pragma unroll
      for (int r = 0; r < 16; r++) {
        int kv = (r & 3) + 8 * (r >> 2) + 4 * hi;
        if (mrow[kv] == 0) s0[r] = -1e9f;
      }
    }
    // ---- no-max softmax: P = exp2(s) ----
    fx16 p0v;
#pragma unroll
    for (int r = 0; r < 16; r++) p0v[r] = fexp2(s0[r]);
    // ---- P -> bf16 fragments in-register, then PV ----
    sh8 pa0, pa1;
    build_pa(p0v, pa0, pa1);
    __builtin_amdgcn_s_setprio(1);
    {
      int sl0 = hi, sl1 = 2 + hi;
      int rd0 = c, rd1 = 32 + c;
      sh8 va = *(const sh8*)&Vt[rd0 * 32 + (sl0 ^ (rd0 & 3)) * 8];
      sh8 vb2 = *(const sh8*)&Vt[rd1 * 32 + (sl0 ^ (rd1 & 3)) * 8];
      o0 = mfma32(va, pa0, o0);
      o1 = mfma32(vb2, pa0, o1);
      va = *(const sh8*)&Vt[rd0 * 32 + (sl1 ^ (rd0 & 3)) * 8];
      vb2 = *(const sh8*)&Vt[rd1 * 32 + (sl1 ^ (rd1 & 3)) * 8];
      o0 = mfma32(va, pa1, o0);
      o1 = mfma32(vb2, pa1, o1);
    }
    __builtin_amdgcn_s_setprio(0);
    // ---- row sums ----
    float sm[8];
#pragma unroll
    for (int r = 0; r < 8; r++) sm[r] = p0v[r] + p0v[r + 8];
#pragma unroll
    for (int w = 4; w >= 1; w >>= 1)
#pragma unroll
      for (int r = 0; r < w; r++) sm[r] += sm[r + w];
    lsum += sm[0];
    if (t + 2 < NT)
      asm volatile("s_waitcnt vmcnt(2)" ::: "memory");  // stage(t+1) landed; t+2 in flight
    else
      asm volatile("s_waitcnt vmcnt(0)" ::: "memory");
    __builtin_amdgcn_s_barrier();
    asm volatile("" ::: "memory");
    cur++; if (cur >= 3) cur = 0;
  }

  // ---- additive combine across kv-groups via LDS (aliases staging; loop done) ----
  float* CB = (float*)&SMEM[0];
  float* CBl = CB + 4 * 32 * 68;
  if (grp == 1) {
#pragma unroll
    for (int k4 = 0; k4 < 4; k4++) {
      fx4 a = {o0[4 * k4], o0[4 * k4 + 1], o0[4 * k4 + 2], o0[4 * k4 + 3]};
      *(fx4*)&CB[(w4 * 32 + c) * 68 + 8 * k4 + 4 * hi] = a;
      fx4 bvv = {o1[4 * k4], o1[4 * k4 + 1], o1[4 * k4 + 2], o1[4 * k4 + 3]};
      *(fx4*)&CB[(w4 * 32 + c) * 68 + 32 + 8 * k4 + 4 * hi] = bvv;
    }
    CBl[w4 * 64 + hi * 32 + c] = lsum;
  }
  __syncthreads();
  if (grp == 0) {
#pragma unroll
    for (int k4 = 0; k4 < 4; k4++) {
      fx4 a = *(const fx4*)&CB[(w4 * 32 + c) * 68 + 8 * k4 + 4 * hi];
      o0[4 * k4] += a[0]; o0[4 * k4 + 1] += a[1]; o0[4 * k4 + 2] += a[2]; o0[4 * k4 + 3] += a[3];
      fx4 bvv = *(const fx4*)&CB[(w4 * 32 + c) * 68 + 32 + 8 * k4 + 4 * hi];
      o1[4 * k4] += bvv[0]; o1[4 * k4 + 1] += bvv[1]; o1[4 * k4 + 2] += bvv[2]; o1[4 * k4 + 3] += bvv[3];
    }
    lsum += CBl[w4 * 64 + hi * 32 + c];
    lsum += __shfl_xor(lsum, 32);
    float linv = 1.0f / lsum;
    unsigned short* Ob = concat + ((size_t)b * Ssz + q0 + c) * Dsz + h * DKsz;
#pragma unroll
    for (int rg = 0; rg < 4; rg++) {
      ushort4 w;
      w.x = f2bf(o0[rg * 4 + 0] * linv);
      w.y = f2bf(o0[rg * 4 + 1] * linv);
      w.z = f2bf(o0[rg * 4 + 2] * linv);
      w.w = f2bf(o0[rg * 4 + 3] * linv);
      *(ushort4*)&Ob[8 * rg + 4 * hi] = w;
      ushort4 w2;
      w2.x = f2bf(o1[rg * 4 + 0] * linv);
      w2.y = f2bf(o1[rg * 4 + 1] * linv);
      w2.z = f2bf(o1[rg * 4 + 2] * linv);
      w2.w = f2bf(o1[rg * 4 + 3] * linv);
      *(ushort4*)&Ob[32 + 8 * rg + 4 * hi] = w2;
    }
  }
}

// ---------------- output projection: out = concat @ Wo^T + bo, 128x64 tile (512 blocks) ----
__global__ __launch_bounds__(256) void outproj_kernel(
    const unsigned short* __restrict__ Xc, const unsigned short* __restrict__ wob,
    const float* __restrict__ bo, float* __restrict__ out) {
  __shared__ __align__(16) unsigned short As[128 * 32];
  __shared__ __align__(16) unsigned short Bs[64 * 32];
  const int m0 = blockIdx.x * 128, n0 = blockIdx.y * 64;
  const int tid = threadIdx.x, lane = tid & 63, wid = tid >> 6;
  const int wm = wid >> 1, wn = wid & 1;
  const int c = lane & 15, g = lane >> 4;
  fx4 acc[4][2] = {};
  for (int k0 = 0; k0 < Dsz; k0 += 32) {
#pragma unroll
    for (int i = 0; i < 2; i++) {
      int e = i * 256 + tid;
      g2l16(Xc + (size_t)(m0 + (e >> 2)) * Dsz + k0 + (e & 3) * 8,
            (char*)As + (size_t)(i * 256 + wid * 64) * 16);
    }
    g2l16(wob + (size_t)(n0 + (tid >> 2)) * Dsz + k0 + (tid & 3) * 8,
          (char*)Bs + (size_t)(wid * 64) * 16);
    __syncthreads();
    sh8 af[4], bfr[2];
#pragma unroll
    for (int m = 0; m < 4; m++)
      af[m] = *(const sh8*)&As[(wm * 64 + m * 16 + c) * 32 + g * 8];
#pragma unroll
    for (int n = 0; n < 2; n++)
      bfr[n] = *(const sh8*)&Bs[(wn * 32 + n * 16 + c) * 32 + g * 8];
#pragma unroll
    for (int m = 0; m < 4; m++)
#pragma unroll
      for (int n = 0; n < 2; n++)
        acc[m][n] = mfma16(af[m], bfr[n], acc[m][n]);
    __syncthreads();
  }
#pragma unroll
  for (int n = 0; n < 2; n++) {
    int j = n0 + wn * 32 + n * 16 + c;
    float bj = bo[j];
#pragma unroll
    for (int m = 0; m < 4; m++)
#pragma unroll
      for (int r = 0; r < 4; r++) {
        int i = m0 + wm * 64 + m * 16 + g * 4 + r;
        out[(size_t)i * Dsz + j] = acc[m][n][r] + bj;
      }
  }
}

extern "C" void kernel_launch(void* const* d_in, const int* in_sizes, int n_in,
                              void* d_out, int out_size, void* d_ws, size_t ws_size,
                              hipStream_t stream) {
  const float* q = (const float*)d_in[0];
  const float* k = (const float*)d_in[1];
  const float* v = (const float*)d_in[2];
  const int* mask = (const int*)d_in[3];
  const float* Wq = (const float*)d_in[4];
  const float* bq = (const float*)d_in[5];
  const float* Wk = (const float*)d_in[6];
  const float* bk = (const float*)d_in[7];
  const float* Wv = (const float*)d_in[8];
  const float* bv = (const float*)d_in[9];
  const float* Wo = (const float*)d_in[10];
  const float* bo = (const float*)d_in[11];
  float* out = (float*)d_out;
  char* ws = (char*)d_ws;
  const size_t MB = 1 << 20;
  unsigned short* wqb = (unsigned short*)(ws + 0 * MB);
  unsigned short* wkb = (unsigned short*)(ws + 2 * MB);
  unsigned short* wvb = (unsigned short*)(ws + 4 * MB);
  unsigned short* wob = (unsigned short*)(ws + 6 * MB);
  unsigned short* qhp = (unsigned short*)(ws + 8 * MB);
  unsigned short* khp = (unsigned short*)(ws + 16 * MB);
  unsigned short* vtp = (unsigned short*)(ws + 24 * MB);
  unsigned short* cc  = (unsigned short*)(ws + 32 * MB);
  int* flag = (int*)(ws + 40 * MB);

  // flag = 0xFFFFFFFF (nonzero == all-ones assumed true until convert proves otherwise)
  hipMemsetAsync(flag, 0xFF, 4, stream);
  hipLaunchKernelGGL(convert_kernel, dim3(1024), dim3(256), 0, stream,
                     Wq, Wk, Wv, Wo, mask, wqb, wkb, wvb, wob, flag);
  hipLaunchKernelGGL(proj_qkv_kernel, dim3(32, 16, 3), dim3(256), 0, stream,
                     q, k, v, wqb, wkb, wvb, bq, bk, bv, qhp, khp, vtp);
  hipLaunchKernelGGL(attn_kernel, dim3(16, 32), dim3(512), 0, stream,
                     qhp, khp, vtp, mask, flag, cc);
  hipLaunchKernelGGL(outproj_kernel, dim3(32, 16), dim3(256), 0, stream,
                     cc, wob, bo, out);
}

// Round 18
// 129.944 us; speedup vs baseline: 1.0061x; 1.0061x over previous
//
#include <hip/hip_runtime.h>
#include <stdint.h>

#define Bsz 2
#define Ssz 2048
#define Dsz 1024
#define Hsz 16
#define DKsz 64

typedef __attribute__((ext_vector_type(8))) short sh8;
typedef __attribute__((ext_vector_type(4))) float fx4;
typedef __attribute__((ext_vector_type(16))) float fx16;
typedef __attribute__((ext_vector_type(4))) unsigned ux4;

__device__ __forceinline__ unsigned short f2bf(float x) {
  uint32_t u = __builtin_bit_cast(uint32_t, x);
  uint32_t r = (u + 0x7fffu + ((u >> 16) & 1u)) >> 16;
  return (unsigned short)r;
}

__device__ __forceinline__ fx4 mfma16(sh8 a, sh8 b, fx4 c) {
  return __builtin_amdgcn_mfma_f32_16x16x32_bf16(a, b, c, 0, 0, 0);
}

__device__ __forceinline__ fx16 mfma32(sh8 a, sh8 b, fx16 c) {
  return __builtin_amdgcn_mfma_f32_32x32x16_bf16(a, b, c, 0, 0, 0);
}

__device__ __forceinline__ void g2l16(const void* g, void* l) {
  __builtin_amdgcn_global_load_lds((const __attribute__((address_space(1))) void*)g,
                                   (__attribute__((address_space(3))) void*)l, 16, 0, 0);
}

__device__ __forceinline__ float fexp2(float x) {
#if __has_builtin(__builtin_amdgcn_exp2f)
  return __builtin_amdgcn_exp2f(x);
#else
  return exp2f(x);
#endif
}

__device__ __forceinline__ unsigned cvtpk(float lo, float hi) {
  unsigned r;
  asm("v_cvt_pk_bf16_f32 %0, %1, %2" : "=v"(r) : "v"(lo), "v"(hi));
  return r;
}

// v_permlane32_swap_b32: after, a = {a.lo, b.lo}, b = {a.hi, b.hi}
__device__ __forceinline__ void plswap(unsigned& a, unsigned& b) {
  asm("v_permlane32_swap_b32 %0, %1" : "+v"(a), "+v"(b));
}

// Build two PV B-operand fragments (k=16 each) from one 32-kv score tile.
__device__ __forceinline__ void build_pa(const fx16& p, sh8& pa0, sh8& pa1) {
  unsigned w0 = cvtpk(p[0], p[1]), w1 = cvtpk(p[2], p[3]);
  unsigned w2 = cvtpk(p[4], p[5]), w3 = cvtpk(p[6], p[7]);
  unsigned w4 = cvtpk(p[8], p[9]), w5 = cvtpk(p[10], p[11]);
  unsigned w6 = cvtpk(p[12], p[13]), w7 = cvtpk(p[14], p[15]);
  plswap(w0, w2);
  plswap(w1, w3);
  ux4 u0 = {w0, w1, w2, w3};
  pa0 = __builtin_bit_cast(sh8, u0);
  plswap(w4, w6);
  plswap(w5, w7);
  ux4 u1 = {w4, w5, w6, w7};
  pa1 = __builtin_bit_cast(sh8, u1);
}

// ------- fp32 -> bf16 conversion of the 4 weights + fused mask all-ones check -------
__global__ __launch_bounds__(256) void convert_kernel(
    const float* __restrict__ wq, const float* __restrict__ wk, const float* __restrict__ wv,
    const float* __restrict__ wo, const int* __restrict__ mask,
    unsigned short* __restrict__ wqb, unsigned short* __restrict__ wkb,
    unsigned short* __restrict__ wvb, unsigned short* __restrict__ wob,
    int* __restrict__ flag) {
  const int NW = Dsz * Dsz / 4;
  const int NC = 4 * NW;
  const int NM = Bsz * Ssz * Ssz / 4;  // mask chunks of int4
  const int total = NC + NM;
  int bad = 0;
  for (int i = blockIdx.x * blockDim.x + threadIdx.x; i < total; i += gridDim.x * blockDim.x) {
    if (i >= NC) {
      int4 m = ((const int4*)mask)[i - NC];
      if (m.x == 0 || m.y == 0 || m.z == 0 || m.w == 0) bad = 1;
      continue;
    }
    int t = i / NW, off = i - t * NW;
    const float* src = (t == 0) ? wq : ((t == 1) ? wk : ((t == 2) ? wv : wo));
    unsigned short* dst = (t == 0) ? wqb : ((t == 1) ? wkb : ((t == 2) ? wvb : wob));
    float4 x = ((const float4*)src)[off];
    ushort4 o;
    o.x = f2bf(x.x); o.y = f2bf(x.y); o.z = f2bf(x.z); o.w = f2bf(x.w);
    ((ushort4*)dst)[off] = o;
  }
  if (bad) atomicAnd(flag, 0);
}

// ---------------- QKV projection GEMM: C = X(fp32) @ W^T + b, bf16 MFMA, 128x64 tile ------
// 128x64 tiles -> 1536 blocks (6/CU) for TLP; A reg-staged 1-deep (R6 structure), B g2l.
// z=0: Q -> qh [B*H,S,64] pre-scaled by CE; z=1: K -> kh; z=2: V -> vt [B*H,64,S].
__global__ __launch_bounds__(256) void proj_qkv_kernel(
    const float* __restrict__ qf, const float* __restrict__ kf, const float* __restrict__ vf,
    const unsigned short* __restrict__ wqb, const unsigned short* __restrict__ wkb,
    const unsigned short* __restrict__ wvb,
    const float* __restrict__ bq, const float* __restrict__ bk, const float* __restrict__ bv,
    unsigned short* __restrict__ qh, unsigned short* __restrict__ kh,
    unsigned short* __restrict__ vt) {
  __shared__ __align__(16) unsigned short SMEM[12288];
  unsigned short* Ts = SMEM;
  const int z = blockIdx.z;
  const float* X = (z == 0) ? qf : ((z == 1) ? kf : vf);
  const unsigned short* W = (z == 0) ? wqb : ((z == 1) ? wkb : wvb);
  const float* bias = (z == 0) ? bq : ((z == 1) ? bk : bv);
  const int m0 = blockIdx.x * 128, n0 = blockIdx.y * 64;
  const int tid = threadIdx.x, lane = tid & 63, wid = tid >> 6;
  const int wm = wid >> 1, wn = wid & 1;
  const int c = lane & 15, g = lane >> 4;
  fx4 acc[4][2] = {};

  auto LOADA = [&](int k0, float4* a) {
#pragma unroll
    for (int i = 0; i < 4; i++) {
      int c4 = i * 256 + tid;
      a[i] = *(const float4*)(X + (size_t)(m0 + (c4 >> 3)) * Dsz + k0 + (c4 & 7) * 4);
    }
  };
  auto WRITEA = [&](const float4* a, unsigned short* As) {
#pragma unroll
    for (int i = 0; i < 4; i++) {
      int c4 = i * 256 + tid;
      uint2 w;
      w.x = cvtpk(a[i].x, a[i].y);
      w.y = cvtpk(a[i].z, a[i].w);
      *(uint2*)&As[(c4 >> 3) * 32 + (c4 & 7) * 4] = w;
    }
  };
  auto G2LB = [&](int k0, unsigned short* Bs) {
    g2l16(W + (size_t)(n0 + (tid >> 2)) * Dsz + k0 + (tid & 3) * 8,
          (char*)Bs + (size_t)(wid * 64) * 16);
  };
  auto COMPUTE = [&](const unsigned short* As, const unsigned short* Bs) {
    sh8 af[4], bfr[2];
#pragma unroll
    for (int m = 0; m < 4; m++)
      af[m] = *(const sh8*)&As[(wm * 64 + m * 16 + c) * 32 + g * 8];
#pragma unroll
    for (int n = 0; n < 2; n++)
      bfr[n] = *(const sh8*)&Bs[(wn * 32 + n * 16 + c) * 32 + g * 8];
#pragma unroll
    for (int m = 0; m < 4; m++)
#pragma unroll
      for (int n = 0; n < 2; n++)
        acc[m][n] = mfma16(af[m], bfr[n], acc[m][n]);
  };

  float4 aA[4], aB[4];
  LOADA(0, aA);
  G2LB(0, SMEM + 8192);
  WRITEA(aA, SMEM);
  __syncthreads();
#pragma unroll 1
  for (int j = 0; j < 16; j++) {
    const int k0 = j * 64;
    if (k0 + 32 < Dsz) { LOADA(k0 + 32, aB); G2LB(k0 + 32, SMEM + 10240); }
    COMPUTE(SMEM, SMEM + 8192);
    if (k0 + 32 < Dsz) WRITEA(aB, SMEM + 4096);
    __syncthreads();
    if (k0 + 64 < Dsz) { LOADA(k0 + 64, aA); G2LB(k0 + 64, SMEM + 8192); }
    if (k0 + 32 < Dsz) COMPUTE(SMEM + 4096, SMEM + 10240);
    if (k0 + 64 < Dsz) WRITEA(aA, SMEM);
    __syncthreads();
  }

  const float CE = 0.18033688011112042f;  // log2(e)/sqrt(64), folded into Q
  if (z < 2) {
    unsigned short* O = (z == 0) ? qh : kh;
    const float sc = (z == 0) ? CE : 1.0f;
#pragma unroll
    for (int n = 0; n < 2; n++) {
      int nl = wn * 32 + n * 16 + c;
      float bj = bias[n0 + nl];
#pragma unroll
      for (int m = 0; m < 4; m++)
#pragma unroll
        for (int r = 0; r < 4; r++) {
          int ml = wm * 64 + m * 16 + g * 4 + r;
          Ts[ml * 72 + nl] = f2bf((acc[m][n][r] + bj) * sc);
        }
    }
    __syncthreads();
    const int h = n0 >> 6;
#pragma unroll
    for (int it = 0; it < 4; it++) {
      int ch = it * 256 + tid;
      int row = ch >> 3, off = ch & 7;
      sh8 dv = *(const sh8*)&Ts[row * 72 + off * 8];
      int i = m0 + row;
      int b = i >> 11, s = i & 2047;
      *(sh8*)&O[(((size_t)(b * Hsz + h) * Ssz + s) << 6) + off * 8] = dv;
    }
  } else {
#pragma unroll
    for (int n = 0; n < 2; n++) {
      int nl = wn * 32 + n * 16 + c;
      float bj = bias[n0 + nl];
#pragma unroll
      for (int m = 0; m < 4; m++)
#pragma unroll
        for (int r = 0; r < 4; r++) {
          int ml = wm * 64 + m * 16 + g * 4 + r;
          Ts[nl * 136 + ml] = f2bf(acc[m][n][r] + bj);
        }
    }
    __syncthreads();
    int b = m0 >> 11, sbase = m0 & 2047;
    const int h = n0 >> 6;
#pragma unroll
    for (int it = 0; it < 4; it++) {
      int ch = it * 256 + tid;
      int row = ch >> 4, off = ch & 15;
      sh8 dv = *(const sh8*)&Ts[row * 136 + off * 8];
      int dk = (n0 + row) & 63;
      *(sh8*)&vt[(size_t)((b * Hsz + h) * DKsz + dk) * Ssz + sbase + off * 8] = dv;
    }
  }
}

// ---------------- flash attention: 32x32 MFMA, KV-split x2, no-max softmax, KVBLK=32 ----
// (the R16 best configuration: 512 blocks x 512 thr, (512,4), KVBLK=32, 36KB LDS)
__global__ __launch_bounds__(512, 4) void attn_kernel(
    const unsigned short* __restrict__ qh, const unsigned short* __restrict__ kh,
    const unsigned short* __restrict__ vt, const int* __restrict__ mask,
    const int* __restrict__ flag, unsigned short* __restrict__ concat) {
  __shared__ __align__(16) unsigned short SMEM[17920];
  const int tid = threadIdx.x, lane = tid & 63, wid = tid >> 6;
  const int grp = wid >> 2, w4 = wid & 3;
  const int fid = blockIdx.y * gridDim.x + blockIdx.x;
  const int logical = (fid & 7) * 64 + (fid >> 3);
  const int bh = logical >> 4, qblk = logical & 15;
  const int b = bh >> 4, h = bh & 15;
  const int q0 = qblk * 128 + w4 * 32;
  const int c = lane & 31, hi = lane >> 5;
  const int kvbase = grp * (Ssz / 2);
  const unsigned short* Qb = qh + ((size_t)bh * Ssz + q0) * DKsz;
  const unsigned short* Kb = kh + (size_t)bh * Ssz * DKsz;
  const unsigned short* Vb = vt + (size_t)bh * DKsz * Ssz;
  const int chk = w4 * 64 + lane;
  const int krow = chk >> 3, ksl = (chk & 7) ^ (krow & 7);
  const int koff = krow * DKsz + ksl * 8;
  const int vrow = chk >> 2, vsl = (chk & 3) ^ (vrow & 3);
  const size_t voff = (size_t)vrow * Ssz + vsl * 8;

  sh8 qf[4];
#pragma unroll
  for (int ks = 0; ks < 4; ks++)
    qf[ks] = *(const sh8*)&Qb[(size_t)c * DKsz + ks * 16 + hi * 8];
  const bool allones = (flag[0] != 0);
  float lsum = 0.f;
  fx16 o0 = {}, o1 = {};

  auto STAGE = [&](int bufi, int kv0) {
    unsigned short* base = SMEM + grp * 8192 + bufi * 4096;
    g2l16(Kb + (size_t)kv0 * DKsz + koff, (char*)base + w4 * 1024);
    g2l16(Vb + kv0 + voff, (char*)(base + 2048) + w4 * 1024);
  };

  const int NT = (Ssz / 2) / 32;
  STAGE(0, kvbase);
  asm volatile("s_waitcnt vmcnt(0)" ::: "memory");
  __builtin_amdgcn_s_barrier();
  asm volatile("" ::: "memory");

  for (int t = 0; t < NT; ++t) {
    const int cur = t & 1;
    const int kv0 = kvbase + t * 32;
    if (t + 1 < NT) STAGE(cur ^ 1, kv0 + 32);
    const unsigned short* Kt = SMEM + grp * 8192 + cur * 4096;
    const unsigned short* Vt = Kt + 2048;
    fx16 s0 = {};
    __builtin_amdgcn_s_setprio(1);
#pragma unroll
    for (int ks = 0; ks < 4; ks++) {
      int sl = (2 * ks + hi) ^ (c & 7);
      sh8 ka = *(const sh8*)&Kt[c * 64 + sl * 8];
      s0 = mfma32(ka, qf[ks], s0);
    }
    __builtin_amdgcn_s_setprio(0);
    if (!allones) {
      const int* mrow = mask + ((size_t)b * Ssz + (q0 + c)) * Ssz + kv0;
#pragma unroll
      for (int r = 0; r < 16; r++) {
        int kv = (r & 3) + 8 * (r >> 2) + 4 * hi;
        if (mrow[kv] == 0) s0[r] = -1e9f;
      }
    }
    fx16 p0v;
#pragma unroll
    for (int r = 0; r < 16; r++) p0v[r] = fexp2(s0[r]);
    sh8 pa0, pa1;
    build_pa(p0v, pa0, pa1);
    __builtin_amdgcn_s_setprio(1);
    {
      int sl0 = hi, sl1 = 2 + hi;
      int rd0 = c, rd1 = 32 + c;
      sh8 va = *(const sh8*)&Vt[rd0 * 32 + (sl0 ^ (rd0 & 3)) * 8];
      sh8 vb2 = *(const sh8*)&Vt[rd1 * 32 + (sl0 ^ (rd1 & 3)) * 8];
      o0 = mfma32(va, pa0, o0);
      o1 = mfma32(vb2, pa0, o1);
      va = *(const sh8*)&Vt[rd0 * 32 + (sl1 ^ (rd0 & 3)) * 8];
      vb2 = *(const sh8*)&Vt[rd1 * 32 + (sl1 ^ (rd1 & 3)) * 8];
      o0 = mfma32(va, pa1, o0);
      o1 = mfma32(vb2, pa1, o1);
    }
    __builtin_amdgcn_s_setprio(0);
    float sm[8];
#pragma unroll
    for (int r = 0; r < 8; r++) sm[r] = p0v[r] + p0v[r + 8];
#pragma unroll
    for (int w = 4; w >= 1; w >>= 1)
#pragma unroll
      for (int r = 0; r < w; r++) sm[r] += sm[r + w];
    lsum += sm[0];
    asm volatile("s_waitcnt vmcnt(0)" ::: "memory");
    __builtin_amdgcn_s_barrier();
    asm volatile("" ::: "memory");
  }

  float* CB = (float*)&SMEM[0];
  float* CBl = CB + 4 * 32 * 68;
  if (grp == 1) {
#pragma unroll
    for (int k4 = 0; k4 < 4; k4++) {
      fx4 a = {o0[4 * k4], o0[4 * k4 + 1], o0[4 * k4 + 2], o0[4 * k4 + 3]};
      *(fx4*)&CB[(w4 * 32 + c) * 68 + 8 * k4 + 4 * hi] = a;
      fx4 bvv = {o1[4 * k4], o1[4 * k4 + 1], o1[4 * k4 + 2], o1[4 * k4 + 3]};
      *(fx4*)&CB[(w4 * 32 + c) * 68 + 32 + 8 * k4 + 4 * hi] = bvv;
    }
    CBl[w4 * 64 + hi * 32 + c] = lsum;
  }
  __syncthreads();
  if (grp == 0) {
#pragma unroll
    for (int k4 = 0; k4 < 4; k4++) {
      fx4 a = *(const fx4*)&CB[(w4 * 32 + c) * 68 + 8 * k4 + 4 * hi];
      o0[4 * k4] += a[0]; o0[4 * k4 + 1] += a[1]; o0[4 * k4 + 2] += a[2]; o0[4 * k4 + 3] += a[3];
      fx4 bvv = *(const fx4*)&CB[(w4 * 32 + c) * 68 + 32 + 8 * k4 + 4 * hi];
      o1[4 * k4] += bvv[0]; o1[4 * k4 + 1] += bvv[1]; o1[4 * k4 + 2] += bvv[2]; o1[4 * k4 + 3] += bvv[3];
    }
    lsum += CBl[w4 * 64 + hi * 32 + c];
    lsum += __shfl_xor(lsum, 32);
    float linv = 1.0f / lsum;
    unsigned short* Ob = concat + ((size_t)b * Ssz + q0 + c) * Dsz + h * DKsz;
#pragma unroll
    for (int rg = 0; rg < 4; rg++) {
      ushort4 w;
      w.x = f2bf(o0[rg * 4 + 0] * linv);
      w.y = f2bf(o0[rg * 4 + 1] * linv);
      w.z = f2bf(o0[rg * 4 + 2] * linv);
      w.w = f2bf(o0[rg * 4 + 3] * linv);
      *(ushort4*)&Ob[8 * rg + 4 * hi] = w;
      ushort4 w2;
      w2.x = f2bf(o1[rg * 4 + 0] * linv);
      w2.y = f2bf(o1[rg * 4 + 1] * linv);
      w2.z = f2bf(o1[rg * 4 + 2] * linv);
      w2.w = f2bf(o1[rg * 4 + 3] * linv);
      *(ushort4*)&Ob[32 + 8 * rg + 4 * hi] = w2;
    }
  }
}

// ---------------- output projection: out = concat @ Wo^T + bo, 128x64 tile (512 blocks) ----
__global__ __launch_bounds__(256) void outproj_kernel(
    const unsigned short* __restrict__ Xc, const unsigned short* __restrict__ wob,
    const float* __restrict__ bo, float* __restrict__ out) {
  __shared__ __align__(16) unsigned short As[128 * 32];
  __shared__ __align__(16) unsigned short Bs[64 * 32];
  const int m0 = blockIdx.x * 128, n0 = blockIdx.y * 64;
  const int tid = threadIdx.x, lane = tid & 63, wid = tid >> 6;
  const int wm = wid >> 1, wn = wid & 1;
  const int c = lane & 15, g = lane >> 4;
  fx4 acc[4][2] = {};
  for (int k0 = 0; k0 < Dsz; k0 += 32) {
#pragma unroll
    for (int i = 0; i < 2; i++) {
      int e = i * 256 + tid;
      g2l16(Xc + (size_t)(m0 + (e >> 2)) * Dsz + k0 + (e & 3) * 8,
            (char*)As + (size_t)(i * 256 + wid * 64) * 16);
    }
    g2l16(wob + (size_t)(n0 + (tid >> 2)) * Dsz + k0 + (tid & 3) * 8,
          (char*)Bs + (size_t)(wid * 64) * 16);
    __syncthreads();
    sh8 af[4], bfr[2];
#pragma unroll
    for (int m = 0; m < 4; m++)
      af[m] = *(const sh8*)&As[(wm * 64 + m * 16 + c) * 32 + g * 8];
#pragma unroll
    for (int n = 0; n < 2; n++)
      bfr[n] = *(const sh8*)&Bs[(wn * 32 + n * 16 + c) * 32 + g * 8];
#pragma unroll
    for (int m = 0; m < 4; m++)
#pragma unroll
      for (int n = 0; n < 2; n++)
        acc[m][n] = mfma16(af[m], bfr[n], acc[m][n]);
    __syncthreads();
  }
#pragma unroll
  for (int n = 0; n < 2; n++) {
    int j = n0 + wn * 32 + n * 16 + c;
    float bj = bo[j];
#pragma unroll
    for (int m = 0; m < 4; m++)
#pragma unroll
      for (int r = 0; r < 4; r++) {
        int i = m0 + wm * 64 + m * 16 + g * 4 + r;
        out[(size_t)i * Dsz + j] = acc[m][n][r] + bj;
      }
  }
}

extern "C" void kernel_launch(void* const* d_in, const int* in_sizes, int n_in,
                              void* d_out, int out_size, void* d_ws, size_t ws_size,
                              hipStream_t stream) {
  const float* q = (const float*)d_in[0];
  const float* k = (const float*)d_in[1];
  const float* v = (const float*)d_in[2];
  const int* mask = (const int*)d_in[3];
  const float* Wq = (const float*)d_in[4];
  const float* bq = (const float*)d_in[5];
  const float* Wk = (const float*)d_in[6];
  const float* bk = (const float*)d_in[7];
  const float* Wv = (const float*)d_in[8];
  const float* bv = (const float*)d_in[9];
  const float* Wo = (const float*)d_in[10];
  const float* bo = (const float*)d_in[11];
  float* out = (float*)d_out;
  char* ws = (char*)d_ws;
  const size_t MB = 1 << 20;
  unsigned short* wqb = (unsigned short*)(ws + 0 * MB);
  unsigned short* wkb = (unsigned short*)(ws + 2 * MB);
  unsigned short* wvb = (unsigned short*)(ws + 4 * MB);
  unsigned short* wob = (unsigned short*)(ws + 6 * MB);
  unsigned short* qhp = (unsigned short*)(ws + 8 * MB);
  unsigned short* khp = (unsigned short*)(ws + 16 * MB);
  unsigned short* vtp = (unsigned short*)(ws + 24 * MB);
  unsigned short* cc  = (unsigned short*)(ws + 32 * MB);
  int* flag = (int*)(ws + 40 * MB);

  // flag = 0xFFFFFFFF (nonzero == all-ones assumed true until convert proves otherwise)
  hipMemsetAsync(flag, 0xFF, 4, stream);
  hipLaunchKernelGGL(convert_kernel, dim3(1024), dim3(256), 0, stream,
                     Wq, Wk, Wv, Wo, mask, wqb, wkb, wvb, wob, flag);
  hipLaunchKernelGGL(proj_qkv_kernel, dim3(32, 16, 3), dim3(256), 0, stream,
                     q, k, v, wqb, wkb, wvb, bq, bk, bv, qhp, khp, vtp);
  hipLaunchKernelGGL(attn_kernel, dim3(16, 32), dim3(512), 0, stream,
                     qhp, khp, vtp, mask, flag, cc);
  hipLaunchKernelGGL(outproj_kernel, dim3(32, 16), dim3(256), 0, stream,
                     cc, wob, bo, out);
}